// Round 11
// baseline (150.064 us; speedup 1.0000x reference)
//
#include <hip/hip_runtime.h>
#include <cstdint>
#include <cstddef>

// SLAYER SRM-alpha constants, rounded-to-nearest f32 from double
#define THETA_F 10.0f
#define DS_C 0.9048374180359595731642491f   // exp(-0.1)
#define DR_C 0.3678794411714423215955238f   // exp(-1.0)
#define CS_C 0.2718281828459045235360287f   // e/10
#define CR_C -54.3656365691809047072057f    // -2*10*e
#define P100_C 4.5399929762484854e-05f      // ds^100 = e^-10
#define QC100_C 4.1079555325e-03f           // 100 * ds^101

typedef unsigned int       u32;
typedef unsigned long long u64;
typedef unsigned short     u16;

// ws layout (8,192,000 bytes = 64*512*2000 bits):
//   w32 region : u32 [64][62][512]  layer-1 spike bits, t in [tb*32,tb*32+32)
//   tail region: u16 [64][512] at byte offset 8,126,464, bits t in [1984,2000)
#define W32_WORDS_PER_B  (62 * 512)
#define TAIL_BYTE_OFF    (64 * 62 * 512 * 4)

// ---------------------------------------------------------------------------
// K1_dual: layer-1 fc + psp_spike, serial bit-exact recursion, TWO channels
// per thread -- (b,h) and (b,h+256) -- interleaved in program order so each
// chain's dependency stalls are filled by the sibling's issue slots (intra-
// wave ILP; arithmetic per chain byte-identical to validated R5/R10 STEP).
// Shared per-step work: one nibble extract + one addr calc; chain 2's table
// read is same vaddr + 4096-byte offset. 256 blocks x 64 thr (1 wave/CU).
// ---------------------------------------------------------------------------
__global__ __launch_bounds__(64) void k1_dual(
    const float* __restrict__ inp,                 // [64][4][2000]
    const float* __restrict__ W1,                  // [512][4]
    u32* __restrict__ w32, u16* __restrict__ tail16)
{
    __shared__ float table[32 * 64];               // rows 0-15: h1, 16-31: h2
    __shared__ alignas(8) unsigned char codes[2048];

    const int tid = threadIdx.x;                   // 0..63
    const int b   = blockIdx.x >> 2;               // 0..63
    const int q   = blockIdx.x & 3;                // h-quarter of [0,256)
    const int h1  = (q << 6) + tid;                // 0..255
    const int h2  = h1 + 256;                      // 256..511

    {
        const float a0 = W1[h1 * 4 + 0], a1 = W1[h1 * 4 + 1];
        const float a2 = W1[h1 * 4 + 2], a3 = W1[h1 * 4 + 3];
        const float b0 = W1[h2 * 4 + 0], b1 = W1[h2 * 4 + 1];
        const float b2 = W1[h2 * 4 + 2], b3 = W1[h2 * 4 + 3];
        // bit-identical to reference einsum contraction (established form)
        for (int c = 0; c < 16; ++c) {
            float v = __fmul_rn(a0, (c & 1) ? 1.0f : 0.0f);
            v = __fadd_rn(v, __fmul_rn(a1, (c & 2) ? 1.0f : 0.0f));
            v = __fadd_rn(v, __fmul_rn(a2, (c & 4) ? 1.0f : 0.0f));
            v = __fadd_rn(v, __fmul_rn(a3, (c & 8) ? 1.0f : 0.0f));
            table[c * 64 + tid] = v;
            float w = __fmul_rn(b0, (c & 1) ? 1.0f : 0.0f);
            w = __fadd_rn(w, __fmul_rn(b1, (c & 2) ? 1.0f : 0.0f));
            w = __fadd_rn(w, __fmul_rn(b2, (c & 4) ? 1.0f : 0.0f));
            w = __fadd_rn(w, __fmul_rn(b3, (c & 8) ? 1.0f : 0.0f));
            table[(c + 16) * 64 + tid] = w;
        }
    }
    // stage all 2000 input codes (4-bit per t)
    for (int t = tid; t < 2000; t += 64) {
        const float v0 = inp[(b * 4 + 0) * 2000 + t];
        const float v1 = inp[(b * 4 + 1) * 2000 + t];
        const float v2 = inp[(b * 4 + 2) * 2000 + t];
        const float v3 = inp[(b * 4 + 3) * 2000 + t];
        codes[t] = (unsigned char)((int)(v0 != 0.0f) | ((int)(v1 != 0.0f) << 1) |
                                   ((int)(v2 != 0.0f) << 2) | ((int)(v3 != 0.0f) << 3));
    }
    if (tid < 48) codes[2000 + tid] = 0;   // pad
    __syncthreads();

    // fetch 8 a-values for BOTH chains; second read = same addr + 4096 B
#define ISSUE2(CW, B1, B2) do {                                               \
        const u32 lo_ = (u32)(CW), hi_ = (u32)((CW) >> 32);                   \
        _Pragma("unroll")                                                     \
        for (int j_ = 0; j_ < 4; ++j_) {                                      \
            const float* p_ = &table[(int)((lo_ >> (8 * j_)) & 15) * 64 + tid]; \
            B1[j_] = p_[0];  B2[j_] = p_[1024];                               \
        }                                                                     \
        _Pragma("unroll")                                                     \
        for (int j_ = 0; j_ < 4; ++j_) {                                      \
            const float* p_ = &table[(int)((hi_ >> (8 * j_)) & 15) * 64 + tid]; \
            B1[4 + j_] = p_[0];  B2[4 + j_] = p_[1024];                       \
        }                                                                     \
    } while (0)

    // one step of BOTH chains, per-chain ops byte-identical to validated STEP
    // (exact reference rounding; TS=1 mults elided; (u>=th)==((u-th)>=0);
    // xr>=0 so cndmask(A+1,A) == A+s bitwise)
#define STEP2(A1, A2, BITPOS) do {                                            \
        const float u1_ = __fadd_rn(__fmul_rn(CS_C, ys1), __fmul_rn(CR_C, yr1)); \
        const float u2_ = __fadd_rn(__fmul_rn(CS_C, ys2), __fmul_rn(CR_C, yr2)); \
        const bool s1_ = (u1_ >= THETA_F);                                    \
        const bool s2_ = (u2_ >= THETA_F);                                    \
        xs1 = __fadd_rn(__fmul_rn(DS_C, xs1), (A1));                          \
        xs2 = __fadd_rn(__fmul_rn(DS_C, xs2), (A2));                          \
        ys1 = __fmul_rn(DS_C, __fadd_rn(ys1, xs1));                           \
        ys2 = __fmul_rn(DS_C, __fadd_rn(ys2, xs2));                           \
        const float A1_ = __fmul_rn(DR_C, xr1);                               \
        const float A2_ = __fmul_rn(DR_C, xr2);                               \
        xr1 = s1_ ? __fadd_rn(A1_, 1.0f) : A1_;                               \
        xr2 = s2_ ? __fadd_rn(A2_, 1.0f) : A2_;                               \
        yr1 = __fmul_rn(DR_C, __fadd_rn(yr1, xr1));                           \
        yr2 = __fmul_rn(DR_C, __fadd_rn(yr2, xr2));                           \
        bits1 = s1_ ? (bits1 | (1u << (BITPOS))) : bits1;                     \
        bits2 = s2_ ? (bits2 | (1u << (BITPOS))) : bits2;                     \
    } while (0)

#define STEP8x2(B1, B2, J0) do {                                              \
        _Pragma("unroll")                                                     \
        for (int j_ = 0; j_ < 8; ++j_) STEP2(B1[j_], B2[j_], (J0) + j_);      \
    } while (0)

    float xs1 = 0.0f, ys1 = 0.0f, xr1 = 0.0f, yr1 = 0.0f;
    float xs2 = 0.0f, ys2 = 0.0f, xr2 = 0.0f, yr2 = 0.0f;
    u32 bits1 = 0, bits2 = 0;
    u32* pw = w32 + (size_t)b * W32_WORDS_PER_B + h1;   // chain2 at +256

    float bA1[8], bA2[8], bB1[8], bB2[8];
    u64 cw = *reinterpret_cast<const u64*>(codes);
    ISSUE2(cw, bA1, bA2);
    u64 c1 = *reinterpret_cast<const u64*>(codes + 8);
    u64 c2 = *reinterpret_cast<const u64*>(codes + 16);
    u64 c3 = *reinterpret_cast<const u64*>(codes + 24);
    u64 c4 = *reinterpret_cast<const u64*>(codes + 32);

    for (int t0 = 0; t0 < 1984; t0 += 32) {
        ISSUE2(c1, bB1, bB2);
        const u64 n1 = *reinterpret_cast<const u64*>(codes + t0 + 40);
        const u64 n2 = *reinterpret_cast<const u64*>(codes + t0 + 48);
        const u64 n3 = *reinterpret_cast<const u64*>(codes + t0 + 56);
        const u64 n4 = *reinterpret_cast<const u64*>(codes + t0 + 64);
        STEP8x2(bA1, bA2, 0);
        ISSUE2(c2, bA1, bA2);
        STEP8x2(bB1, bB2, 8);
        ISSUE2(c3, bB1, bB2);
        STEP8x2(bA1, bA2, 16);
        ISSUE2(c4, bA1, bA2);
        STEP8x2(bB1, bB2, 24);
        pw[0] = bits1; pw[256] = bits2;
        pw += 512; bits1 = 0; bits2 = 0;
        c1 = n1; c2 = n2; c3 = n3; c4 = n4;
    }
    // tail: bA holds t=1984..1991 (issued with c4 at t0=1952); c1 = codes[1992..2000)
    ISSUE2(c1, bB1, bB2);
    STEP8x2(bA1, bA2, 0);
    STEP8x2(bB1, bB2, 8);
    tail16[b * 512 + h1] = (u16)bits1;
    tail16[b * 512 + h2] = (u16)bits2;

#undef STEP8x2
#undef STEP2
#undef ISSUE2
}

// ---------------------------------------------------------------------------
// K2: a2[b,o,t] = ascending-h sum of W2[o,h]*s1[b,h,t] (unchanged, validated).
// ---------------------------------------------------------------------------
__global__ __launch_bounds__(256) void k2_fc2(
    const u32* __restrict__ w32, const u16* __restrict__ tail16,
    const float* __restrict__ W2,                  // [2][512]
    float* __restrict__ a2)                        // [128][2000]
{
    __shared__ float w2s[1024];
    __shared__ u32 stage[4096];                    // [local tb 0..7][h 0..511]

    const int tid = threadIdx.x;
    const int b  = blockIdx.x >> 3;
    const int it = blockIdx.x & 7;

    for (int j = tid; j < 1024; j += 256) w2s[j] = W2[j];
    #pragma unroll
    for (int k = 0; k < 16; ++k) {
        const int l = tid + (k << 8);              // 0..4095
        const int gtb = (it << 3) + (l >> 9);
        u32 v = 0;
        if (gtb < 62)       v = w32[((size_t)b * 62 + gtb) * 512 + (l & 511)];
        else if (gtb == 62) v = (u32)tail16[b * 512 + (l & 511)];
        stage[l] = v;
    }
    __syncthreads();

    const int t = (it << 8) + tid;
    if (t < 2000) {
        const u32* srow = stage + ((tid >> 5) << 9);
        const int sh = tid & 31;
        float acc0 = 0.0f, acc1 = 0.0f;
        #pragma unroll 8
        for (int hh = 0; hh < 512; ++hh) {
            const bool on = (srow[hh] >> sh) & 1u;
            acc0 = __fadd_rn(acc0, on ? w2s[hh] : 0.0f);
            acc1 = __fadd_rn(acc1, on ? w2s[512 + hh] : 0.0f);
        }
        a2[(size_t)(b * 2 + 0) * 2000 + t] = acc0;
        a2[(size_t)(b * 2 + 1) * 2000 + t] = acc1;
    }
}

// ---------------------------------------------------------------------------
// K3all: merged tail (unchanged, validated R10) — k3lin (a2->U) + spike gen
// with 64-step refractory warm-up (U->s2) + k3lin (s2->psp), LDS-staged.
// grid 32 x block 80 (4 chains x 20 chunks of 100).
// ---------------------------------------------------------------------------
__global__ __launch_bounds__(80) void k3all(
    const float* __restrict__ a2, float* __restrict__ out)
{
    __shared__ float U[4][2000];
    __shared__ unsigned char s2b[4][2000];
    __shared__ float ex[4][20], ey[4][20], px[4][20], py[4][20];

    const int tid = threadIdx.x;                   // 0..79
    const int lc  = tid / 20;                      // 0..3
    const int ck  = tid - lc * 20;                 // 0..19
    const int chain = blockIdx.x * 4 + lc;         // 0..127

    // ---- phase 0: a2 -> U (k3lin form, validated R6/R7/R10) ----
    {
        const float* segi = a2 + (size_t)chain * 2000 + ck * 100;
        float* segU = &U[lc][ck * 100];
        float X = 0.0f, Y = 0.0f;
        for (int g = 0; g < 25; ++g) {
            float4 qv = *reinterpret_cast<const float4*>(segi + 4 * g);
            float z;
            z = __fmul_rn(CS_C, Y); X = __fmaf_rn(DS_C, X, qv.x);
            Y = __fmul_rn(DS_C, __fadd_rn(Y, X)); qv.x = z;
            z = __fmul_rn(CS_C, Y); X = __fmaf_rn(DS_C, X, qv.y);
            Y = __fmul_rn(DS_C, __fadd_rn(Y, X)); qv.y = z;
            z = __fmul_rn(CS_C, Y); X = __fmaf_rn(DS_C, X, qv.z);
            Y = __fmul_rn(DS_C, __fadd_rn(Y, X)); qv.z = z;
            z = __fmul_rn(CS_C, Y); X = __fmaf_rn(DS_C, X, qv.w);
            Y = __fmul_rn(DS_C, __fadd_rn(Y, X)); qv.w = z;
            *reinterpret_cast<float4*>(segU + 4 * g) = qv;
        }
        ex[lc][ck] = X; ey[lc][ck] = Y;
    }
    __syncthreads();
    if (tid < 4) {
        float x = 0.0f, y = 0.0f;
        for (int c = 0; c < 20; ++c) {
            px[tid][c] = x; py[tid][c] = y;
            const float xn = __fmaf_rn(P100_C, x, ex[tid][c]);
            const float yn = __fadd_rn(
                __fmaf_rn(QC100_C, x, __fmul_rn(P100_C, y)), ey[tid][c]);
            x = xn; y = yn;
        }
    }
    __syncthreads();
    {
        float xh = px[lc][ck], yh = py[lc][ck];
        float* segU = &U[lc][ck * 100];
        if (ck != 0) {
            for (int g = 0; g < 25; ++g) {
                float4 qv = *reinterpret_cast<const float4*>(segU + 4 * g);
                qv.x = __fmaf_rn(CS_C, yh, qv.x);
                xh = __fmul_rn(DS_C, xh); yh = __fmul_rn(DS_C, __fadd_rn(yh, xh));
                qv.y = __fmaf_rn(CS_C, yh, qv.y);
                xh = __fmul_rn(DS_C, xh); yh = __fmul_rn(DS_C, __fadd_rn(yh, xh));
                qv.z = __fmaf_rn(CS_C, yh, qv.z);
                xh = __fmul_rn(DS_C, xh); yh = __fmul_rn(DS_C, __fadd_rn(yh, xh));
                qv.w = __fmaf_rn(CS_C, yh, qv.w);
                xh = __fmul_rn(DS_C, xh); yh = __fmul_rn(DS_C, __fadd_rn(yh, xh));
                *reinterpret_cast<float4*>(segU + 4 * g) = qv;
            }
        }
    }
    __syncthreads();

    // ---- phase 1: U -> s2 bytes (64-step warm-up, validated R7/R10) ----
    {
        float xr2 = 0.0f, yr2 = 0.0f;
#define RSTEP(UV) do {                                                        \
        const float u_ = __fadd_rn((UV), __fmul_rn(CR_C, yr2));               \
        const bool sp_ = (u_ >= THETA_F);                                     \
        const float A_ = __fmul_rn(DR_C, xr2);                                \
        xr2 = sp_ ? __fadd_rn(A_, 1.0f) : A_;                                 \
        yr2 = __fmul_rn(DR_C, __fadd_rn(yr2, xr2));                           \
    } while (0)
        if (ck != 0) {
            const float* wseg = &U[lc][ck * 100 - 64];
            #pragma unroll
            for (int g = 0; g < 16; ++g) {
                const float4 qv = *reinterpret_cast<const float4*>(wseg + 4 * g);
                RSTEP(qv.x); RSTEP(qv.y); RSTEP(qv.z); RSTEP(qv.w);
            }
        }
        const float* eseg = &U[lc][ck * 100];
        unsigned char* ob = &s2b[lc][ck * 100];
        for (int g = 0; g < 25; ++g) {
            const float4 qv = *reinterpret_cast<const float4*>(eseg + 4 * g);
            const float uv[4] = {qv.x, qv.y, qv.z, qv.w};
            #pragma unroll
            for (int j = 0; j < 4; ++j) {
                const float u_ = __fadd_rn(uv[j], __fmul_rn(CR_C, yr2));
                const bool sp_ = (u_ >= THETA_F);
                ob[4 * g + j] = sp_ ? 1 : 0;
                const float A_ = __fmul_rn(DR_C, xr2);
                xr2 = sp_ ? __fadd_rn(A_, 1.0f) : A_;
                yr2 = __fmul_rn(DR_C, __fadd_rn(yr2, xr2));
            }
        }
#undef RSTEP
    }
    __syncthreads();

    // ---- phase 2: s2 -> out (final psp readout, validated form) ----
    float* sego = out + (size_t)chain * 2000 + ck * 100;
    {
        const unsigned char* si = &s2b[lc][ck * 100];
        float X = 0.0f, Y = 0.0f;
        for (int j = 0; j < 100; ++j) {
            const float a = (float)si[j];
            const float z = __fmul_rn(CS_C, Y);
            X = __fmaf_rn(DS_C, X, a);
            Y = __fmul_rn(DS_C, __fadd_rn(Y, X));
            sego[j] = z;
        }
        ex[lc][ck] = X; ey[lc][ck] = Y;
    }
    __syncthreads();
    if (tid < 4) {
        float x = 0.0f, y = 0.0f;
        for (int c = 0; c < 20; ++c) {
            px[tid][c] = x; py[tid][c] = y;
            const float xn = __fmaf_rn(P100_C, x, ex[tid][c]);
            const float yn = __fadd_rn(
                __fmaf_rn(QC100_C, x, __fmul_rn(P100_C, y)), ey[tid][c]);
            x = xn; y = yn;
        }
    }
    __syncthreads();
    {
        float xh = px[lc][ck], yh = py[lc][ck];
        if (ck != 0) {
            for (int j = 0; j < 100; ++j) {
                sego[j] = __fmaf_rn(CS_C, yh, sego[j]);
                xh = __fmul_rn(DS_C, xh);
                yh = __fmul_rn(DS_C, __fadd_rn(yh, xh));
            }
        }
    }
}

extern "C" void kernel_launch(void* const* d_in, const int* in_sizes, int n_in,
                              void* d_out, int out_size, void* d_ws, size_t ws_size,
                              hipStream_t stream)
{
    const float* inp = (const float*)d_in[0];  // [64][4][2000]
    const float* W1  = (const float*)d_in[1];  // [512][4]
    const float* W2  = (const float*)d_in[2];  // [2][512]
    float* out = (float*)d_out;                // [64][2][2000]

    u32* w32    = (u32*)d_ws;
    u16* tail16 = (u16*)((char*)d_ws + TAIL_BYTE_OFF);

    k1_dual<<<dim3(256), dim3(64), 0, stream>>>(inp, W1, w32, tail16);
    k2_fc2<<<dim3(512), dim3(256), 0, stream>>>(w32, tail16, W2, out);
    k3all<<<dim3(32), dim3(80), 0, stream>>>(out, out);
}

// Round 12
// 137.661 us; speedup vs baseline: 1.0901x; 1.0901x over previous
//
#include <hip/hip_runtime.h>
#include <cstdint>
#include <cstddef>

// SLAYER SRM-alpha constants, rounded-to-nearest f32 from double
#define THETA_F 10.0f
#define DS_C 0.9048374180359595731642491f   // exp(-0.1)
#define DR_C 0.3678794411714423215955238f   // exp(-1.0)
#define CS_C 0.2718281828459045235360287f   // e/10
#define CR_C -54.3656365691809047072057f    // -2*10*e
#define P40_C 1.8315638888734179e-02f       // ds^40 = e^-4
#define Q40_C 6.6290701607045023e-01f       // 40 * ds^41 = 40*e^-4.1

typedef unsigned int       u32;
typedef unsigned long long u64;
typedef unsigned short     u16;

// ws layout (8,192,000 bytes = 64*512*2000 bits):
//   w32 region : u32 [64][62][512]  layer-1 spike bits, t in [tb*32,tb*32+32)
//   tail region: u16 [64][512] at byte offset 8,126,464, bits t in [1984,2000)
#define W32_WORDS_PER_B  (62 * 512)
#define TAIL_BYTE_OFF    (64 * 62 * 512 * 4)

// ---------------------------------------------------------------------------
// K1: layer-1 fc + psp_spike — SERIAL, bit-exact. BYTE-IDENTICAL to the
// R10-validated kernel (86 µs). Established floor: wall = one wave's serial
// 2000-step chain; R4/R5/R8/R9/R11 bracket every alternative (TLP pairing,
// ILP dual-chain, chunk-parallel) as slower or incorrect.
// ---------------------------------------------------------------------------
__global__ __launch_bounds__(128) void k1_layer1(
    const float* __restrict__ inp,                 // [64][4][2000]
    const float* __restrict__ W1,                  // [512][4]
    u32* __restrict__ w32, u16* __restrict__ tail16)
{
    __shared__ float table[16 * 128];
    __shared__ alignas(8) unsigned char codes[2048];

    const int tid = threadIdx.x;                   // 0..127
    const int b   = blockIdx.x >> 2;               // 0..63
    const int h   = ((blockIdx.x & 3) << 7) + tid; // 0..511

    const float w0 = W1[h * 4 + 0];
    const float w1 = W1[h * 4 + 1];
    const float w2 = W1[h * 4 + 2];
    const float w3 = W1[h * 4 + 3];
    for (int c = 0; c < 16; ++c) {
        float v = __fmul_rn(w0, (c & 1) ? 1.0f : 0.0f);
        v = __fadd_rn(v, __fmul_rn(w1, (c & 2) ? 1.0f : 0.0f));
        v = __fadd_rn(v, __fmul_rn(w2, (c & 4) ? 1.0f : 0.0f));
        v = __fadd_rn(v, __fmul_rn(w3, (c & 8) ? 1.0f : 0.0f));
        table[c * 128 + tid] = v;
    }
    for (int t = tid; t < 2000; t += 128) {
        const float v0 = inp[(b * 4 + 0) * 2000 + t];
        const float v1 = inp[(b * 4 + 1) * 2000 + t];
        const float v2 = inp[(b * 4 + 2) * 2000 + t];
        const float v3 = inp[(b * 4 + 3) * 2000 + t];
        codes[t] = (unsigned char)((int)(v0 != 0.0f) | ((int)(v1 != 0.0f) << 1) |
                                   ((int)(v2 != 0.0f) << 2) | ((int)(v3 != 0.0f) << 3));
    }
    if (tid < 48) codes[2000 + tid] = 0;   // pad
    __syncthreads();

#define ISSUE(CW, BUF) do {                                                   \
        const u32 lo_ = (u32)(CW), hi_ = (u32)((CW) >> 32);                   \
        BUF[0] = table[((lo_      ) & 15) * 128 + tid];                       \
        BUF[1] = table[((lo_ >>  8) & 15) * 128 + tid];                       \
        BUF[2] = table[((lo_ >> 16) & 15) * 128 + tid];                       \
        BUF[3] = table[((lo_ >> 24) & 15) * 128 + tid];                       \
        BUF[4] = table[((hi_      ) & 15) * 128 + tid];                       \
        BUF[5] = table[((hi_ >>  8) & 15) * 128 + tid];                       \
        BUF[6] = table[((hi_ >> 16) & 15) * 128 + tid];                       \
        BUF[7] = table[((hi_ >> 24) & 15) * 128 + tid];                       \
    } while (0)

#define STEP(AV, BITPOS) do {                                                 \
        const float u_ = __fadd_rn(__fmul_rn(CS_C, ys), __fmul_rn(CR_C, yr)); \
        const bool sp_ = (u_ >= THETA_F);                                     \
        xs = __fadd_rn(__fmul_rn(DS_C, xs), (AV));                            \
        ys = __fmul_rn(DS_C, __fadd_rn(ys, xs));                              \
        const float A_ = __fmul_rn(DR_C, xr);                                 \
        xr = sp_ ? __fadd_rn(A_, 1.0f) : A_;                                  \
        yr = __fmul_rn(DR_C, __fadd_rn(yr, xr));                              \
        bits = sp_ ? (bits | (1u << (BITPOS))) : bits;                        \
    } while (0)

#define STEP8(BUF, J0) do {                                                   \
        _Pragma("unroll")                                                     \
        for (int j_ = 0; j_ < 8; ++j_) STEP(BUF[j_], (J0) + j_);              \
    } while (0)

    float xs = 0.0f, ys = 0.0f, xr = 0.0f, yr = 0.0f;
    u32 bits = 0;
    u32* pw = w32 + (size_t)b * W32_WORDS_PER_B + h;

    float bA[8], bB[8];
    u64 cw = *reinterpret_cast<const u64*>(codes);
    ISSUE(cw, bA);
    u64 c1 = *reinterpret_cast<const u64*>(codes + 8);
    u64 c2 = *reinterpret_cast<const u64*>(codes + 16);
    u64 c3 = *reinterpret_cast<const u64*>(codes + 24);
    u64 c4 = *reinterpret_cast<const u64*>(codes + 32);

    for (int t0 = 0; t0 < 1984; t0 += 32) {
        ISSUE(c1, bB);
        const u64 n1 = *reinterpret_cast<const u64*>(codes + t0 + 40);
        const u64 n2 = *reinterpret_cast<const u64*>(codes + t0 + 48);
        const u64 n3 = *reinterpret_cast<const u64*>(codes + t0 + 56);
        const u64 n4 = *reinterpret_cast<const u64*>(codes + t0 + 64);
        STEP8(bA, 0);
        ISSUE(c2, bA);
        STEP8(bB, 8);
        ISSUE(c3, bB);
        STEP8(bA, 16);
        ISSUE(c4, bA);
        STEP8(bB, 24);
        *pw = bits; pw += 512; bits = 0;
        c1 = n1; c2 = n2; c3 = n3; c4 = n4;
    }
    ISSUE(c1, bB);
    STEP8(bA, 0);
    STEP8(bB, 8);
    tail16[b * 512 + h] = (u16)bits;

#undef STEP8
#undef STEP
#undef ISSUE
}

// ---------------------------------------------------------------------------
// K2: a2[b,o,t] = ascending-h sum of W2[o,h]*s1[b,h,t] (byte-identical, valid.)
// ---------------------------------------------------------------------------
__global__ __launch_bounds__(256) void k2_fc2(
    const u32* __restrict__ w32, const u16* __restrict__ tail16,
    const float* __restrict__ W2,                  // [2][512]
    float* __restrict__ a2)                        // [128][2000]
{
    __shared__ float w2s[1024];
    __shared__ u32 stage[4096];                    // [local tb 0..7][h 0..511]

    const int tid = threadIdx.x;
    const int b  = blockIdx.x >> 3;
    const int it = blockIdx.x & 7;

    for (int j = tid; j < 1024; j += 256) w2s[j] = W2[j];
    #pragma unroll
    for (int k = 0; k < 16; ++k) {
        const int l = tid + (k << 8);              // 0..4095
        const int gtb = (it << 3) + (l >> 9);
        u32 v = 0;
        if (gtb < 62)       v = w32[((size_t)b * 62 + gtb) * 512 + (l & 511)];
        else if (gtb == 62) v = (u32)tail16[b * 512 + (l & 511)];
        stage[l] = v;
    }
    __syncthreads();

    const int t = (it << 8) + tid;
    if (t < 2000) {
        const u32* srow = stage + ((tid >> 5) << 9);
        const int sh = tid & 31;
        float acc0 = 0.0f, acc1 = 0.0f;
        #pragma unroll 8
        for (int hh = 0; hh < 512; ++hh) {
            const bool on = (srow[hh] >> sh) & 1u;
            acc0 = __fadd_rn(acc0, on ? w2s[hh] : 0.0f);
            acc1 = __fadd_rn(acc1, on ? w2s[512 + hh] : 0.0f);
        }
        a2[(size_t)(b * 2 + 0) * 2000 + t] = acc0;
        a2[(size_t)(b * 2 + 1) * 2000 + t] = acc1;
    }
}

// ---------------------------------------------------------------------------
// K3all: merged tail, now 50 CHUNKS of 40 steps (was 20 of 100) — halves or
// better every serial segment. Same validated mechanism: k3lin zero-state +
// M^L prefix + homogeneous correction (L=40 now), spike gen with refractory
// warm-up (ck=1: EXACT 40-step warm from t=0, strictly safer than R10;
// ck>=2: 64-step warm, validated class), final psp readout.
// grid 32 x block 200 (4 chains x 50 chunks). LDS ~43 KB.
// ---------------------------------------------------------------------------
__global__ __launch_bounds__(200) void k3all(
    const float* __restrict__ a2, float* __restrict__ out)
{
    __shared__ float U[4][2000];
    __shared__ unsigned char s2b[4][2000];
    __shared__ float ex[4][50], ey[4][50], px[4][50], py[4][50];

    const int tid = threadIdx.x;                   // 0..199
    const int lc  = tid / 50;                      // 0..3
    const int ck  = tid - lc * 50;                 // 0..49
    const int chain = blockIdx.x * 4 + lc;         // 0..127

    // ---- phase 0: a2 -> U (zero-state alpha filter per 40-chunk) ----
    {
        const float* segi = a2 + (size_t)chain * 2000 + ck * 40;
        float* segU = &U[lc][ck * 40];
        float X = 0.0f, Y = 0.0f;
        for (int g = 0; g < 10; ++g) {
            float4 qv = *reinterpret_cast<const float4*>(segi + 4 * g);
            float z;
            z = __fmul_rn(CS_C, Y); X = __fmaf_rn(DS_C, X, qv.x);
            Y = __fmul_rn(DS_C, __fadd_rn(Y, X)); qv.x = z;
            z = __fmul_rn(CS_C, Y); X = __fmaf_rn(DS_C, X, qv.y);
            Y = __fmul_rn(DS_C, __fadd_rn(Y, X)); qv.y = z;
            z = __fmul_rn(CS_C, Y); X = __fmaf_rn(DS_C, X, qv.z);
            Y = __fmul_rn(DS_C, __fadd_rn(Y, X)); qv.z = z;
            z = __fmul_rn(CS_C, Y); X = __fmaf_rn(DS_C, X, qv.w);
            Y = __fmul_rn(DS_C, __fadd_rn(Y, X)); qv.w = z;
            *reinterpret_cast<float4*>(segU + 4 * g) = qv;
        }
        ex[lc][ck] = X; ey[lc][ck] = Y;
    }
    __syncthreads();
    if (tid < 4) {                                 // M^40 prefix over 50 chunks
        float x = 0.0f, y = 0.0f;
        for (int c = 0; c < 50; ++c) {
            px[tid][c] = x; py[tid][c] = y;
            const float xn = __fmaf_rn(P40_C, x, ex[tid][c]);
            const float yn = __fadd_rn(
                __fmaf_rn(Q40_C, x, __fmul_rn(P40_C, y)), ey[tid][c]);
            x = xn; y = yn;
        }
    }
    __syncthreads();
    {
        float xh = px[lc][ck], yh = py[lc][ck];
        float* segU = &U[lc][ck * 40];
        if (ck != 0) {                             // homogeneous correction
            for (int g = 0; g < 10; ++g) {
                float4 qv = *reinterpret_cast<const float4*>(segU + 4 * g);
                qv.x = __fmaf_rn(CS_C, yh, qv.x);
                xh = __fmul_rn(DS_C, xh); yh = __fmul_rn(DS_C, __fadd_rn(yh, xh));
                qv.y = __fmaf_rn(CS_C, yh, qv.y);
                xh = __fmul_rn(DS_C, xh); yh = __fmul_rn(DS_C, __fadd_rn(yh, xh));
                qv.z = __fmaf_rn(CS_C, yh, qv.z);
                xh = __fmul_rn(DS_C, xh); yh = __fmul_rn(DS_C, __fadd_rn(yh, xh));
                qv.w = __fmaf_rn(CS_C, yh, qv.w);
                xh = __fmul_rn(DS_C, xh); yh = __fmul_rn(DS_C, __fadd_rn(yh, xh));
                *reinterpret_cast<float4*>(segU + 4 * g) = qv;
            }
        }
    }
    __syncthreads();

    // ---- phase 1: U -> s2 bytes (refractory warm-up + emit) ----
    {
        float xr2 = 0.0f, yr2 = 0.0f;
#define RSTEP(UV) do {                                                        \
        const float u_ = __fadd_rn((UV), __fmul_rn(CR_C, yr2));               \
        const bool sp_ = (u_ >= THETA_F);                                     \
        const float A_ = __fmul_rn(DR_C, xr2);                                \
        xr2 = sp_ ? __fadd_rn(A_, 1.0f) : A_;                                 \
        yr2 = __fmul_rn(DR_C, __fadd_rn(yr2, xr2));                           \
    } while (0)
        if (ck == 1) {                             // EXACT: warm from t=0
            const float* wseg = &U[lc][0];
            #pragma unroll
            for (int g = 0; g < 10; ++g) {
                const float4 qv = *reinterpret_cast<const float4*>(wseg + 4 * g);
                RSTEP(qv.x); RSTEP(qv.y); RSTEP(qv.z); RSTEP(qv.w);
            }
        } else if (ck >= 2) {                      // 64-step warm (validated)
            const float* wseg = &U[lc][ck * 40 - 64];
            #pragma unroll
            for (int g = 0; g < 16; ++g) {
                const float4 qv = *reinterpret_cast<const float4*>(wseg + 4 * g);
                RSTEP(qv.x); RSTEP(qv.y); RSTEP(qv.z); RSTEP(qv.w);
            }
        }
        const float* eseg = &U[lc][ck * 40];
        unsigned char* ob = &s2b[lc][ck * 40];
        for (int g = 0; g < 10; ++g) {
            const float4 qv = *reinterpret_cast<const float4*>(eseg + 4 * g);
            const float uv[4] = {qv.x, qv.y, qv.z, qv.w};
            #pragma unroll
            for (int j = 0; j < 4; ++j) {
                const float u_ = __fadd_rn(uv[j], __fmul_rn(CR_C, yr2));
                const bool sp_ = (u_ >= THETA_F);
                ob[4 * g + j] = sp_ ? 1 : 0;
                const float A_ = __fmul_rn(DR_C, xr2);
                xr2 = sp_ ? __fadd_rn(A_, 1.0f) : A_;
                yr2 = __fmul_rn(DR_C, __fadd_rn(yr2, xr2));
            }
        }
#undef RSTEP
    }
    __syncthreads();

    // ---- phase 2: s2 -> out (final psp readout, same chunked filter) ----
    float* sego = out + (size_t)chain * 2000 + ck * 40;
    {
        const unsigned char* si = &s2b[lc][ck * 40];
        float X = 0.0f, Y = 0.0f;
        for (int j = 0; j < 40; ++j) {
            const float a = (float)si[j];
            const float z = __fmul_rn(CS_C, Y);
            X = __fmaf_rn(DS_C, X, a);
            Y = __fmul_rn(DS_C, __fadd_rn(Y, X));
            sego[j] = z;
        }
        ex[lc][ck] = X; ey[lc][ck] = Y;
    }
    __syncthreads();
    if (tid < 4) {
        float x = 0.0f, y = 0.0f;
        for (int c = 0; c < 50; ++c) {
            px[tid][c] = x; py[tid][c] = y;
            const float xn = __fmaf_rn(P40_C, x, ex[tid][c]);
            const float yn = __fadd_rn(
                __fmaf_rn(Q40_C, x, __fmul_rn(P40_C, y)), ey[tid][c]);
            x = xn; y = yn;
        }
    }
    __syncthreads();
    {
        float xh = px[lc][ck], yh = py[lc][ck];
        if (ck != 0) {
            for (int j = 0; j < 40; ++j) {
                sego[j] = __fmaf_rn(CS_C, yh, sego[j]);
                xh = __fmul_rn(DS_C, xh);
                yh = __fmul_rn(DS_C, __fadd_rn(yh, xh));
            }
        }
    }
}

extern "C" void kernel_launch(void* const* d_in, const int* in_sizes, int n_in,
                              void* d_out, int out_size, void* d_ws, size_t ws_size,
                              hipStream_t stream)
{
    const float* inp = (const float*)d_in[0];  // [64][4][2000]
    const float* W1  = (const float*)d_in[1];  // [512][4]
    const float* W2  = (const float*)d_in[2];  // [2][512]
    float* out = (float*)d_out;                // [64][2][2000]

    u32* w32    = (u32*)d_ws;
    u16* tail16 = (u16*)((char*)d_ws + TAIL_BYTE_OFF);

    k1_layer1<<<dim3(256), dim3(128), 0, stream>>>(inp, W1, w32, tail16);
    k2_fc2<<<dim3(512), dim3(256), 0, stream>>>(w32, tail16, W2, out);
    k3all<<<dim3(32), dim3(200), 0, stream>>>(out, out);
}